// Round 15
// baseline (196.367 us; speedup 1.0000x reference)
//
#include <hip/hip_runtime.h>
#include <hip/hip_bf16.h>

#define BN 8192
#define LOGB 13

typedef __attribute__((ext_vector_type(8))) short short8;
typedef __attribute__((ext_vector_type(4))) float f32x4;

__device__ __forceinline__ float tanh_fast(float x) {
  x = fminf(fmaxf(x, -15.f), 15.f);
  float t = __expf(2.f * x);
  return (t - 1.f) / (t + 1.f);
}

__device__ __forceinline__ unsigned short f2bf(float f) {
  union { __hip_bfloat16 h; unsigned short u; } cv;
  cv.h = __float2bfloat16(f);
  return cv.u;
}

__device__ __forceinline__ float bf2f(unsigned short s) {
  return __uint_as_float(((unsigned)s) << 16);
}

__device__ __forceinline__ uint2 pack4bf(float a, float b, float c, float d) {
  unsigned lo = (unsigned)f2bf(a) | ((unsigned)f2bf(b) << 16);
  unsigned hi = (unsigned)f2bf(c) | ((unsigned)f2bf(d) << 16);
  return make_uint2(lo, hi);
}

// ---- prep: weight packs (+ u-column extraction) in one kernel ----
__device__ __forceinline__ void pack_one(
    const float* __restrict__ W, unsigned short* __restrict__ dst,
    int i, int Nsrc, int Ksrc, int nKs, int skip) {
  int j = i & 7, l = (i >> 3) & 63, fi = i >> 9;
  int ks = fi % nKs, nt = fi / nKs;
  int n = nt * 16 + (l & 15);
  int k = ks * 32 + ((l >> 4) << 3) + j;
  if (skip >= 0 && k >= skip) k++;
  float v = (n < Nsrc && k < Ksrc) ? W[n * Ksrc + k] : 0.f;
  dst[i] = f2bf(v);
}

__global__ __launch_bounds__(256) void k_prep_pack(
    const float* __restrict__ s0, unsigned short* __restrict__ d0,
    const float* __restrict__ s1, unsigned short* __restrict__ d1,
    const float* __restrict__ s2, unsigned short* __restrict__ d2,
    const float* __restrict__ s3, unsigned short* __restrict__ d3,
    const float* __restrict__ s4, unsigned short* __restrict__ d4,
    const float* __restrict__ s5, unsigned short* __restrict__ d5,
    const float* __restrict__ s6, unsigned short* __restrict__ d6,
    const float* __restrict__ s7, unsigned short* __restrict__ d7,
    const float* __restrict__ s8, unsigned short* __restrict__ d8,
    const float* __restrict__ s9, unsigned short* __restrict__ d9,
    float* __restrict__ wu0, float* __restrict__ wu1) {
  int i = blockIdx.x * 256 + threadIdx.x;
  if (i < 25600) { pack_one(s0, d0, i, 400, 65, 2, 32); return; }
  i -= 25600;
  if (i < 126464) { pack_one(s1, d1, i, 300, 400, 13, -1); return; }
  i -= 126464;
  if (i < 25600) { pack_one(s2, d2, i, 400, 65, 2, 32); return; }
  i -= 25600;
  if (i < 126464) { pack_one(s3, d3, i, 300, 400, 13, -1); return; }
  i -= 126464;
  if (i < 25600) { pack_one(s4, d4, i, 400, 64, 2, -1); return; }
  i -= 25600;
  if (i < 126464) { pack_one(s5, d5, i, 300, 400, 13, -1); return; }
  i -= 126464;
  if (i < 20480) { pack_one(s6, d6, i, 64, 300, 10, -1); return; }
  i -= 20480;
  if (i < 2048) { pack_one(s7, d7, i, 64, 33, 1, -1); return; }
  i -= 2048;
  if (i < 8192) { pack_one(s8, d8, i, 64, 128, 4, -1); return; }
  i -= 8192;
  if (i < 2048) { pack_one(s9, d9, i, 32, 64, 2, -1); return; }
  i -= 2048;
  if (i < 400) { wu0[i] = s0[i * 65 + 32]; return; }
  i -= 400;
  if (i < 400) { wu1[i] = s2[i * 65 + 32]; return; }
}

// ---------------- bottom-up via MFMA (R12, proven) ----------------
__global__ __launch_bounds__(512, 4) void k_up_mfma(
    const float* __restrict__ x, const float* __restrict__ u,
    const unsigned short* __restrict__ w1f, const float* __restrict__ w1raw,
    const float* __restrict__ b1,
    const unsigned short* __restrict__ w2f, const float* __restrict__ b2,
    const unsigned short* __restrict__ w3f, const float* __restrict__ b3,
    float* __restrict__ msg_up, int phase, int node_base) {
  __shared__ __align__(16) unsigned short Xs[64 * 40];
  __shared__ __align__(16) unsigned short Hs[64 * 136];
  __shared__ __align__(16) unsigned short H2s[64 * 72];
  __shared__ float Ms[2][64][32];
  __shared__ float Red[2][64];
  __shared__ float u_s[64];
  const int tid = threadIdx.x, w = tid >> 6, l = tid & 63;
  const int lr = l & 15, lh = l >> 4;
  const int mt = w & 3, nh = w >> 2;
  const int r0 = blockIdx.x * 64;
  const short8* w1v = (const short8*)w1f;
  const short8* w2v = (const short8*)w2f;
  const short8* w3v = (const short8*)w3f;

  const int nsteps = phase ? 1 : 3;
  const int sroot = 3 + blockIdx.y;

  for (int step = 0; step < nsteps; step++) {
    int node, sl = 0, sr = 0, os = -1;
    bool haveCh;
    if (phase) {
      node = node_base + blockIdx.y; haveCh = true;
    } else {
      switch (step) {
        case 0: node = 2 * sroot + 1; haveCh = false; os = 0; break;
        case 1: node = 2 * sroot + 2; haveCh = false; os = 1; break;
        default: node = sroot; haveCh = true; sl = 0; sr = 1; os = -1; break;
      }
    }
    const int rbase = (node << LOGB) + r0;

    for (int f = tid; f < 64 * 32; f += 512) {
      int r = f >> 5, c = f & 31;
      Xs[r * 40 + c] = f2bf(x[(rbase + r) * 32 + c]);
    }
    if (tid < 64) u_s[tid] = u[rbase + tid];
    if (haveCh) {
      for (int f = tid; f < 64 * 64; f += 512) {
        int r = f >> 6, c = f & 63;
        float v;
        if (phase)
          v = (c < 32) ? msg_up[(((2 * node + 1) << LOGB) + r0 + r) * 32 + c]
                       : msg_up[(((2 * node + 2) << LOGB) + r0 + r) * 32 + (c - 32)];
        else
          v = (c < 32) ? Ms[sl][r][c] : Ms[sr][r][c - 32];
        Hs[r * 136 + 64 + c] = f2bf(tanh_fast(v));
      }
    }
    __syncthreads();

    f32x4 acc1[2];
#pragma unroll
    for (int t = 0; t < 2; t++) acc1[t] = (f32x4)(0.f);
    {
      short8 a = *(const short8*)&Xs[(mt * 16 + lr) * 40 + lh * 8];
#pragma unroll
      for (int t = 0; t < 2; t++)
        acc1[t] = __builtin_amdgcn_mfma_f32_16x16x32_bf16(a, w1v[(nh * 2 + t) * 64 + l], acc1[t], 0, 0, 0);
    }
    float v1[2][4];
    {
      float vsq[4] = {0.f, 0.f, 0.f, 0.f};
#pragma unroll
      for (int t = 0; t < 2; t++) {
        int n = (nh * 2 + t) * 16 + lr;
        float wu = w1raw[n * 33 + 32];
        float bb = b1[n];
#pragma unroll
        for (int r = 0; r < 4; r++) {
          float vv = acc1[t][r] + u_s[mt * 16 + lh * 4 + r] * wu + bb;
          v1[t][r] = vv;
          vsq[r] += vv * vv;
        }
      }
#pragma unroll
      for (int r = 0; r < 4; r++) {
        float s = vsq[r];
        s += __shfl_xor(s, 1, 64);
        s += __shfl_xor(s, 2, 64);
        s += __shfl_xor(s, 4, 64);
        s += __shfl_xor(s, 8, 64);
        if (lr == 0) Red[nh][mt * 16 + lh * 4 + r] = s;
      }
    }
    __syncthreads();
#pragma unroll
    for (int r = 0; r < 4; r++) {
      int row = mt * 16 + lh * 4 + r;
      float inv = 1.f / fmaxf(sqrtf(Red[0][row] + Red[1][row]), 1e-12f);
#pragma unroll
      for (int t = 0; t < 2; t++)
        Hs[row * 136 + (nh * 2 + t) * 16 + lr] = f2bf(tanh_fast(v1[t][r] * inv));
    }
    __syncthreads();

    f32x4 acc2[2];
#pragma unroll
    for (int t = 0; t < 2; t++) acc2[t] = (f32x4)(0.f);
    const int ksmax = haveCh ? 4 : 2;
#pragma unroll
    for (int ks = 0; ks < 4; ks++) {
      if (ks < ksmax) {
        short8 a = *(const short8*)&Hs[(mt * 16 + lr) * 136 + ks * 32 + lh * 8];
#pragma unroll
        for (int t = 0; t < 2; t++)
          acc2[t] = __builtin_amdgcn_mfma_f32_16x16x32_bf16(a, w2v[((nh * 2 + t) * 4 + ks) * 64 + l], acc2[t], 0, 0, 0);
      }
    }
#pragma unroll
    for (int t = 0; t < 2; t++) {
      int n = (nh * 2 + t) * 16 + lr;
      float bb = b2[n];
#pragma unroll
      for (int r = 0; r < 4; r++)
        H2s[(mt * 16 + lh * 4 + r) * 72 + n] = f2bf(tanh_fast(acc2[t][r] + bb));
    }
    __syncthreads();

    f32x4 acc3 = (f32x4)(0.f);
#pragma unroll
    for (int ks = 0; ks < 2; ks++) {
      short8 a = *(const short8*)&H2s[(mt * 16 + lr) * 72 + ks * 32 + lh * 8];
      acc3 = __builtin_amdgcn_mfma_f32_16x16x32_bf16(a, w3v[(nh * 2 + ks) * 64 + l], acc3, 0, 0, 0);
    }
    float v3[4];
    {
      float bb = b3[nh * 16 + lr];
#pragma unroll
      for (int r = 0; r < 4; r++) {
        v3[r] = acc3[r] + bb;
        float s = v3[r] * v3[r];
        s += __shfl_xor(s, 1, 64);
        s += __shfl_xor(s, 2, 64);
        s += __shfl_xor(s, 4, 64);
        s += __shfl_xor(s, 8, 64);
        if (lr == 0) Red[nh][mt * 16 + lh * 4 + r] = s;
      }
    }
    __syncthreads();
    {
      const int n = nh * 16 + lr;
#pragma unroll
      for (int r = 0; r < 4; r++) {
        int row = mt * 16 + lh * 4 + r;
        float inv = 1.f / fmaxf(sqrtf(Red[0][row] + Red[1][row]), 1e-12f);
        float mv = v3[r] * inv;
        msg_up[(rbase + row) * 32 + n] = mv;
        if (os >= 0) Ms[os][row][n] = mv;
      }
    }
    __syncthreads();
  }
}

// ---------------- mb chain: 2 parallel subtree walks via blockIdx.y ----------------
// y=0 walks {0,1,3,4}; y=1 walks {0,2,5,6}. Node 0 computed by both (bit-identical,
// duplicate msg_in[1],[2] writes benign). Chain depth 7 -> 4.
__global__ __launch_bounds__(512, 2) void k_mb_fused(
    const float* __restrict__ msg_up,
    const unsigned short* __restrict__ w1f, const unsigned short* __restrict__ w2f,
    const unsigned short* __restrict__ w3f,
    const float* __restrict__ b1, const float* __restrict__ b2, const float* __restrict__ b3,
    float* __restrict__ msg_in_out) {
  __shared__ __align__(16) unsigned short H1s[32 * 424];
  __shared__ __align__(16) unsigned short H2s[32 * 328];
  __shared__ __align__(16) unsigned char XR[32 * 72 * 2];
  unsigned short* Xs = (unsigned short*)XR;
  float* RedM = (float*)XR;
  const int tid = threadIdx.x;
  const int r0 = blockIdx.x * 32;
  const int w = tid >> 6, l = tid & 63;
  const int lr = l & 15, lh = l >> 4;
  const short8* w1v = (const short8*)w1f;
  const short8* w2v = (const short8*)w2f;
  const short8* w3v = (const short8*)w3f;

  const int sub = blockIdx.y;   // 0 or 1
  const int seq1 = 1 + sub, seq2 = 3 + 2 * sub, seq3 = 4 + 2 * sub;
  const int seq[4] = {0, seq1, seq2, seq3};

  for (int f = tid; f < 32 * 16; f += 512)
    H1s[(f >> 4) * 424 + 400 + (f & 15)] = 0;
  for (int f = tid; f < 32 * 16; f += 512)
    H2s[(f >> 4) * 328 + 304 + (f & 15)] = 0;

  for (int step = 0; step < 4; step++) {
    const int node = seq[step];
    const int rbase = (node << LOGB) + r0;
    // msg_in for this node was written by THIS block at its parent step -> L2 read-back.
    for (int f = tid; f < 32 * 64; f += 512) {
      int r = f >> 6, c = f & 63;
      float v;
      if (c < 32) v = msg_up[(rbase + r) * 32 + c];
      else v = (node > 0) ? msg_in_out[(rbase + r) * 32 + (c - 32)] : 0.f;
      Xs[r * 72 + c] = f2bf(tanh_fast(v));
    }
    __syncthreads();

    // ---- layer 1 (swapped) ----
    const int nb1 = (w == 0) ? 0 : (3 * w + 1);
    const int nc1 = (w == 0) ? 4 : 3;
    f32x4 acc1[4][2];
#pragma unroll
    for (int i = 0; i < 4; i++)
#pragma unroll
      for (int m = 0; m < 2; m++) acc1[i][m] = (f32x4)(0.f);
    __builtin_amdgcn_s_setprio(1);
#pragma unroll
    for (int ks = 0; ks < 2; ks++) {
      short8 bx[2];
#pragma unroll
      for (int m = 0; m < 2; m++)
        bx[m] = *(const short8*)&Xs[(m * 16 + lr) * 72 + ks * 32 + lh * 8];
      short8 aw[4];
#pragma unroll
      for (int nt = 0; nt < 4; nt++)
        if (nt < nc1) aw[nt] = w1v[((nb1 + nt) * 2 + ks) * 64 + l];
#pragma unroll
      for (int nt = 0; nt < 4; nt++)
        if (nt < nc1)
#pragma unroll
          for (int m = 0; m < 2; m++)
            acc1[nt][m] = __builtin_amdgcn_mfma_f32_16x16x32_bf16(aw[nt], bx[m], acc1[nt][m], 0, 0, 0);
    }
    __builtin_amdgcn_s_setprio(0);
#pragma unroll
    for (int nt = 0; nt < 4; nt++)
      if (nt < nc1) {
        int n0 = (nb1 + nt) * 16 + lh * 4;
        float4 bb = *(const float4*)&b1[n0];
#pragma unroll
        for (int m = 0; m < 2; m++) {
          float h0 = fmaxf(acc1[nt][m][0] + bb.x, 0.f);
          float h1 = fmaxf(acc1[nt][m][1] + bb.y, 0.f);
          float h2 = fmaxf(acc1[nt][m][2] + bb.z, 0.f);
          float h3 = fmaxf(acc1[nt][m][3] + bb.w, 0.f);
          *(uint2*)&H1s[(m * 16 + lr) * 424 + n0] = pack4bf(h0, h1, h2, h3);
        }
      }
    __syncthreads();

    // ---- layer 2 (swapped) ----
    const int nb2 = (w < 3) ? 3 * w : (9 + 2 * (w - 3));
    const int nc2 = (w < 3) ? 3 : 2;
    f32x4 acc2[3][2];
#pragma unroll
    for (int i = 0; i < 3; i++)
#pragma unroll
      for (int m = 0; m < 2; m++) acc2[i][m] = (f32x4)(0.f);
    __builtin_amdgcn_s_setprio(1);
#pragma unroll 2
    for (int ks = 0; ks < 13; ks++) {
      short8 bh[2];
#pragma unroll
      for (int m = 0; m < 2; m++)
        bh[m] = *(const short8*)&H1s[(m * 16 + lr) * 424 + ks * 32 + lh * 8];
      short8 aw[3];
#pragma unroll
      for (int nt = 0; nt < 3; nt++)
        if (nt < nc2) aw[nt] = w2v[((nb2 + nt) * 13 + ks) * 64 + l];
#pragma unroll
      for (int nt = 0; nt < 3; nt++)
        if (nt < nc2)
#pragma unroll
          for (int m = 0; m < 2; m++)
            acc2[nt][m] = __builtin_amdgcn_mfma_f32_16x16x32_bf16(aw[nt], bh[m], acc2[nt][m], 0, 0, 0);
    }
    __builtin_amdgcn_s_setprio(0);
#pragma unroll
    for (int nt = 0; nt < 3; nt++)
      if (nt < nc2) {
        int n0 = (nb2 + nt) * 16 + lh * 4;
        float b2v[4];
#pragma unroll
        for (int r = 0; r < 4; r++) {
          int n = n0 + r;
          b2v[r] = (n < 300) ? b2[n] : 0.f;
        }
#pragma unroll
        for (int m = 0; m < 2; m++) {
          float hv[4];
#pragma unroll
          for (int r = 0; r < 4; r++)
            hv[r] = (n0 + r < 300) ? fmaxf(acc2[nt][m][r] + b2v[r], 0.f) : 0.f;
          *(uint2*)&H2s[(m * 16 + lr) * 328 + n0] = pack4bf(hv[0], hv[1], hv[2], hv[3]);
        }
      }
    __syncthreads();

    // ---- layer 3 (swapped): ALL 8 waves; wave = (m-half = w>>2, n-tile = w&3) ----
    float v3[4];
    {
      const int mL3 = w >> 2;
      const int nt3 = w & 3;
      f32x4 acc3 = (f32x4)(0.f);
      __builtin_amdgcn_s_setprio(1);
#pragma unroll 2
      for (int ks = 0; ks < 10; ks++) {
        short8 bh = *(const short8*)&H2s[(mL3 * 16 + lr) * 328 + ks * 32 + lh * 8];
        short8 aw = w3v[(nt3 * 10 + ks) * 64 + l];
        acc3 = __builtin_amdgcn_mfma_f32_16x16x32_bf16(aw, bh, acc3, 0, 0, 0);
      }
      __builtin_amdgcn_s_setprio(0);
      int n0 = nt3 * 16 + lh * 4;
      float4 bb = *(const float4*)&b3[n0];
      v3[0] = acc3[0] + bb.x;
      v3[1] = acc3[1] + bb.y;
      v3[2] = acc3[2] + bb.z;
      v3[3] = acc3[3] + bb.w;
      float ss = v3[0] * v3[0] + v3[1] * v3[1] + v3[2] * v3[2] + v3[3] * v3[3];
      ss += __shfl_xor(ss, 16, 64);
      ss += __shfl_xor(ss, 32, 64);
      if (l < 16) RedM[nt3 * 32 + mL3 * 16 + l] = ss;
    }
    __syncthreads();
    {
      const int mL3 = w >> 2;
      const int nt3 = w & 3;
      const int row = mL3 * 16 + lr;
      float ss = RedM[0 * 32 + row] + RedM[1 * 32 + row] + RedM[2 * 32 + row] + RedM[3 * 32 + row];
      float inv = 1.f / fmaxf(sqrtf(ss), 1e-12f);
      const int child = 2 * node + 1 + (nt3 >> 1);
      const int ccol0 = (nt3 & 1) * 16 + lh * 4;
      float4 o;
      o.x = v3[0] * inv; o.y = v3[1] * inv;
      o.z = v3[2] * inv; o.w = v3[3] * inv;
      *(float4*)&msg_in_out[((child << LOGB) + r0 + row) * 32 + ccol0] = o;
    }
    __syncthreads();
  }
}

// ---------------- Q nets: 512 threads, 64 rows/block, swapped MFMA (R12-proven) ----------------
__global__ __launch_bounds__(512, 4) void k_q_mfma(
    const float* __restrict__ msg_up, const float* __restrict__ u,
    const float* __restrict__ msg_in,
    const unsigned short* __restrict__ w1fA, const unsigned short* __restrict__ w2fA,
    const float* __restrict__ wuA, const float* __restrict__ b1A,
    const float* __restrict__ b2A, const float* __restrict__ w3A, const float* __restrict__ b3A,
    const unsigned short* __restrict__ w1fB, const unsigned short* __restrict__ w2fB,
    const float* __restrict__ wuB, const float* __restrict__ b1B,
    const float* __restrict__ b2B, const float* __restrict__ w3B, const float* __restrict__ b3B,
    float* __restrict__ out) {
  __shared__ __align__(16) unsigned char sraw[64 * 72 * 2];
  __shared__ __align__(16) unsigned short H1s[64 * 424];
  __shared__ float u_s[64];
  unsigned short* Xs = (unsigned short*)sraw;
  float* Red = (float*)sraw;

  const int tid = threadIdx.x;
  const int net = blockIdx.y;
  const unsigned short* w1f = net ? w1fB : w1fA;
  const unsigned short* w2f = net ? w2fB : w2fA;
  const float* wua = net ? wuB : wuA;
  const float* b1 = net ? b1B : b1A;
  const float* b2 = net ? b2B : b2A;
  const float* w3 = net ? w3B : w3A;
  const float* b3 = net ? b3B : b3A;
  const int r0 = blockIdx.x * 64;
  const int node = r0 >> LOGB;
  const int has_parent = (node > 0);
  const short8* w1v = (const short8*)w1f;
  const short8* w2v = (const short8*)w2f;

  {
    const int r = tid >> 3, seg = tid & 7;
    float4 v0, v1;
    if (seg < 4) {
      const float4* p = (const float4*)&msg_up[(r0 + r) * 32 + seg * 8];
      v0 = p[0]; v1 = p[1];
    } else if (has_parent) {
      const float4* p = (const float4*)&msg_in[(r0 + r) * 32 + (seg - 4) * 8];
      v0 = p[0]; v1 = p[1];
    } else {
      v0 = make_float4(0.f, 0.f, 0.f, 0.f); v1 = v0;
    }
    unsigned short tmp[8] = {f2bf(v0.x), f2bf(v0.y), f2bf(v0.z), f2bf(v0.w),
                             f2bf(v1.x), f2bf(v1.y), f2bf(v1.z), f2bf(v1.w)};
    *(short8*)&Xs[r * 72 + seg * 8] = *(const short8*)tmp;
  }
  for (int f = tid; f < 64 * 16; f += 512)
    H1s[(f >> 4) * 424 + 400 + (f & 15)] = 0;
  if (tid < 64) u_s[tid] = u[r0 + tid];
  __syncthreads();

  const int w = tid >> 6, l = tid & 63;
  const int lr = l & 15, lh = l >> 4;

  const int nb1 = (w == 0) ? 0 : (3 * w + 1);
  const int nc1 = (w == 0) ? 4 : 3;
  f32x4 acc1[4][4];
#pragma unroll
  for (int i = 0; i < 4; i++)
#pragma unroll
    for (int m = 0; m < 4; m++) acc1[i][m] = (f32x4)(0.f);
  __builtin_amdgcn_s_setprio(1);
#pragma unroll
  for (int ks = 0; ks < 2; ks++) {
    short8 bx[4];
#pragma unroll
    for (int m = 0; m < 4; m++)
      bx[m] = *(const short8*)&Xs[(m * 16 + lr) * 72 + ks * 32 + lh * 8];
    short8 aw[4];
#pragma unroll
    for (int nt = 0; nt < 4; nt++)
      if (nt < nc1) aw[nt] = w1v[((nb1 + nt) * 2 + ks) * 64 + l];
#pragma unroll
    for (int nt = 0; nt < 4; nt++)
      if (nt < nc1)
#pragma unroll
        for (int m = 0; m < 4; m++)
          acc1[nt][m] = __builtin_amdgcn_mfma_f32_16x16x32_bf16(aw[nt], bx[m], acc1[nt][m], 0, 0, 0);
  }
  __builtin_amdgcn_s_setprio(0);
#pragma unroll
  for (int nt = 0; nt < 4; nt++)
    if (nt < nc1) {
      int n0 = (nb1 + nt) * 16 + lh * 4;
      float4 bb = *(const float4*)&b1[n0];
      float4 wu = *(const float4*)&wua[n0];
#pragma unroll
      for (int m = 0; m < 4; m++) {
        float uv = u_s[m * 16 + lr];
        float h0 = fmaxf(acc1[nt][m][0] + uv * wu.x + bb.x, 0.f);
        float h1 = fmaxf(acc1[nt][m][1] + uv * wu.y + bb.y, 0.f);
        float h2 = fmaxf(acc1[nt][m][2] + uv * wu.z + bb.z, 0.f);
        float h3 = fmaxf(acc1[nt][m][3] + uv * wu.w + bb.w, 0.f);
        *(uint2*)&H1s[(m * 16 + lr) * 424 + n0] = pack4bf(h0, h1, h2, h3);
      }
    }
  __syncthreads();

  const int nb2 = (w < 3) ? 3 * w : (9 + 2 * (w - 3));
  const int nc2 = (w < 3) ? 3 : 2;
  f32x4 acc2[3][4];
#pragma unroll
  for (int i = 0; i < 3; i++)
#pragma unroll
    for (int m = 0; m < 4; m++) acc2[i][m] = (f32x4)(0.f);
  __builtin_amdgcn_s_setprio(1);
#pragma unroll 2
  for (int ks = 0; ks < 13; ks++) {
    short8 bh[4];
#pragma unroll
    for (int m = 0; m < 4; m++)
      bh[m] = *(const short8*)&H1s[(m * 16 + lr) * 424 + ks * 32 + lh * 8];
    short8 aw[3];
#pragma unroll
    for (int nt = 0; nt < 3; nt++)
      if (nt < nc2) aw[nt] = w2v[((nb2 + nt) * 13 + ks) * 64 + l];
#pragma unroll
    for (int nt = 0; nt < 3; nt++)
      if (nt < nc2)
#pragma unroll
        for (int m = 0; m < 4; m++)
          acc2[nt][m] = __builtin_amdgcn_mfma_f32_16x16x32_bf16(aw[nt], bh[m], acc2[nt][m], 0, 0, 0);
  }
  __builtin_amdgcn_s_setprio(0);
  float part[4];
#pragma unroll
  for (int m = 0; m < 4; m++) part[m] = 0.f;
#pragma unroll
  for (int nt = 0; nt < 3; nt++)
    if (nt < nc2) {
      int n0 = (nb2 + nt) * 16 + lh * 4;
      float b2v[4], w3v4[4];
#pragma unroll
      for (int r = 0; r < 4; r++) {
        int n = n0 + r;
        b2v[r] = (n < 300) ? b2[n] : 0.f;
        w3v4[r] = (n < 300) ? w3[n] : 0.f;
      }
#pragma unroll
      for (int m = 0; m < 4; m++)
#pragma unroll
        for (int r = 0; r < 4; r++) {
          float h = fmaxf(acc2[nt][m][r] + b2v[r], 0.f);
          part[m] = fmaf(h, w3v4[r], part[m]);
        }
    }
#pragma unroll
  for (int m = 0; m < 4; m++) {
    float p = part[m];
    p += __shfl_xor(p, 16, 64);
    p += __shfl_xor(p, 32, 64);
    if (l < 16) Red[w * 64 + m * 16 + l] = p;
  }
  __syncthreads();
  if (tid < 64) {
    float q = b3[0];
#pragma unroll
    for (int i = 0; i < 8; i++) q += Red[i * 64 + tid];
    out[(r0 + tid) * 2 + net] = q;
  }
}

extern "C" void kernel_launch(void* const* d_in, const int* in_sizes, int n_in,
                              void* d_out, int out_size, void* d_ws, size_t ws_size,
                              hipStream_t stream) {
  const float* x    = (const float*)d_in[0];
  const float* u    = (const float*)d_in[1];
  const float* up1w = (const float*)d_in[2];  const float* up1b = (const float*)d_in[3];
  const float* up2w = (const float*)d_in[4];  const float* up2b = (const float*)d_in[5];
  const float* up3w = (const float*)d_in[6];  const float* up3b = (const float*)d_in[7];
  const float* q1w1 = (const float*)d_in[8];  const float* q1b1 = (const float*)d_in[9];
  const float* q1w2 = (const float*)d_in[10]; const float* q1b2 = (const float*)d_in[11];
  const float* q1w3 = (const float*)d_in[12]; const float* q1b3 = (const float*)d_in[13];
  const float* q2w1 = (const float*)d_in[14]; const float* q2b1 = (const float*)d_in[15];
  const float* q2w2 = (const float*)d_in[16]; const float* q2b2 = (const float*)d_in[17];
  const float* q2w3 = (const float*)d_in[18]; const float* q2b3 = (const float*)d_in[19];
  const float* mbw1 = (const float*)d_in[20]; const float* mbb1 = (const float*)d_in[21];
  const float* mbw2 = (const float*)d_in[22]; const float* mbb2 = (const float*)d_in[23];
  const float* mbw3 = (const float*)d_in[24]; const float* mbb3 = (const float*)d_in[25];
  float* out = (float*)d_out;
  float* ws  = (float*)d_ws;

  float* msg_up = ws;
  float* msg_in = msg_up + 15 * BN * 32;
  unsigned short* frag = (unsigned short*)(msg_in + 15 * BN * 32);
  unsigned short* q1w1f = frag;
  unsigned short* q1w2f = q1w1f + 25600;
  unsigned short* q2w1f = q1w2f + 126464;
  unsigned short* q2w2f = q2w1f + 25600;
  unsigned short* mbw1f = q2w2f + 126464;
  unsigned short* mbw2f = mbw1f + 25600;
  unsigned short* mbw3f = mbw2f + 126464;
  unsigned short* up1f  = mbw3f + 20480;
  unsigned short* up2f  = up1f + 2048;
  unsigned short* up3f  = up2f + 8192;
  float* wuQ1 = (float*)(up3f + 2048);
  float* wuQ2 = wuQ1 + 400;

  k_prep_pack<<<dim3((489760 + 255) / 256), dim3(256), 0, stream>>>(
      q1w1, q1w1f, q1w2, q1w2f, q2w1, q2w1f, q2w2, q2w2f,
      mbw1, mbw1f, mbw2, mbw2f, mbw3, mbw3f,
      up1w, up1f, up2w, up2f, up3w, up3f, wuQ1, wuQ2);

  k_up_mfma<<<dim3(BN / 64, 4), dim3(512), 0, stream>>>(
      x, u, up1f, up1w, up1b, up2f, up2b, up3f, up3b, msg_up, 0, 0);
  k_up_mfma<<<dim3(BN / 64, 2), dim3(512), 0, stream>>>(
      x, u, up1f, up1w, up1b, up2f, up2b, up3f, up3b, msg_up, 1, 1);
  k_up_mfma<<<dim3(BN / 64, 1), dim3(512), 0, stream>>>(
      x, u, up1f, up1w, up1b, up2f, up2b, up3f, up3b, msg_up, 1, 0);

  k_mb_fused<<<dim3(BN / 32, 2), dim3(512), 0, stream>>>(
      msg_up, mbw1f, mbw2f, mbw3f, mbb1, mbb2, mbb3, msg_in);

  k_q_mfma<<<dim3(15 * (BN / 64), 2), dim3(512), 0, stream>>>(
      msg_up, u, msg_in,
      q1w1f, q1w2f, wuQ1, q1b1, q1b2, q1w3, q1b3,
      q2w1f, q2w2f, wuQ2, q2b1, q2b2, q2w3, q2b3,
      out);
}

// Round 16
// 186.748 us; speedup vs baseline: 1.0515x; 1.0515x over previous
//
#include <hip/hip_runtime.h>
#include <hip/hip_bf16.h>

#define BN 8192
#define LOGB 13

typedef __attribute__((ext_vector_type(8))) short short8;
typedef __attribute__((ext_vector_type(4))) float f32x4;

__device__ __forceinline__ float tanh_fast(float x) {
  x = fminf(fmaxf(x, -15.f), 15.f);
  float t = __expf(2.f * x);
  return (t - 1.f) / (t + 1.f);
}

__device__ __forceinline__ unsigned short f2bf(float f) {
  union { __hip_bfloat16 h; unsigned short u; } cv;
  cv.h = __float2bfloat16(f);
  return cv.u;
}

__device__ __forceinline__ float bf2f(unsigned short s) {
  return __uint_as_float(((unsigned)s) << 16);
}

__device__ __forceinline__ uint2 pack4bf(float a, float b, float c, float d) {
  unsigned lo = (unsigned)f2bf(a) | ((unsigned)f2bf(b) << 16);
  unsigned hi = (unsigned)f2bf(c) | ((unsigned)f2bf(d) << 16);
  return make_uint2(lo, hi);
}

// ---- prep: weight packs (+ u-column extraction) in one kernel ----
__device__ __forceinline__ void pack_one(
    const float* __restrict__ W, unsigned short* __restrict__ dst,
    int i, int Nsrc, int Ksrc, int nKs, int skip) {
  int j = i & 7, l = (i >> 3) & 63, fi = i >> 9;
  int ks = fi % nKs, nt = fi / nKs;
  int n = nt * 16 + (l & 15);
  int k = ks * 32 + ((l >> 4) << 3) + j;
  if (skip >= 0 && k >= skip) k++;
  float v = (n < Nsrc && k < Ksrc) ? W[n * Ksrc + k] : 0.f;
  dst[i] = f2bf(v);
}

__global__ __launch_bounds__(256) void k_prep_pack(
    const float* __restrict__ s0, unsigned short* __restrict__ d0,
    const float* __restrict__ s1, unsigned short* __restrict__ d1,
    const float* __restrict__ s2, unsigned short* __restrict__ d2,
    const float* __restrict__ s3, unsigned short* __restrict__ d3,
    const float* __restrict__ s4, unsigned short* __restrict__ d4,
    const float* __restrict__ s5, unsigned short* __restrict__ d5,
    const float* __restrict__ s6, unsigned short* __restrict__ d6,
    const float* __restrict__ s7, unsigned short* __restrict__ d7,
    const float* __restrict__ s8, unsigned short* __restrict__ d8,
    const float* __restrict__ s9, unsigned short* __restrict__ d9,
    float* __restrict__ wu0, float* __restrict__ wu1) {
  int i = blockIdx.x * 256 + threadIdx.x;
  if (i < 25600) { pack_one(s0, d0, i, 400, 65, 2, 32); return; }
  i -= 25600;
  if (i < 126464) { pack_one(s1, d1, i, 300, 400, 13, -1); return; }
  i -= 126464;
  if (i < 25600) { pack_one(s2, d2, i, 400, 65, 2, 32); return; }
  i -= 25600;
  if (i < 126464) { pack_one(s3, d3, i, 300, 400, 13, -1); return; }
  i -= 126464;
  if (i < 25600) { pack_one(s4, d4, i, 400, 64, 2, -1); return; }
  i -= 25600;
  if (i < 126464) { pack_one(s5, d5, i, 300, 400, 13, -1); return; }
  i -= 126464;
  if (i < 20480) { pack_one(s6, d6, i, 64, 300, 10, -1); return; }
  i -= 20480;
  if (i < 2048) { pack_one(s7, d7, i, 64, 33, 1, -1); return; }
  i -= 2048;
  if (i < 8192) { pack_one(s8, d8, i, 64, 128, 4, -1); return; }
  i -= 8192;
  if (i < 2048) { pack_one(s9, d9, i, 32, 64, 2, -1); return; }
  i -= 2048;
  if (i < 400) { wu0[i] = s0[i * 65 + 32]; return; }
  i -= 400;
  if (i < 400) { wu1[i] = s2[i * 65 + 32]; return; }
}

// ---------------- bottom-up via MFMA ----------------
__global__ __launch_bounds__(512, 4) void k_up_mfma(
    const float* __restrict__ x, const float* __restrict__ u,
    const unsigned short* __restrict__ w1f, const float* __restrict__ w1raw,
    const float* __restrict__ b1,
    const unsigned short* __restrict__ w2f, const float* __restrict__ b2,
    const unsigned short* __restrict__ w3f, const float* __restrict__ b3,
    float* __restrict__ msg_up, int phase, int node_base) {
  __shared__ __align__(16) unsigned short Xs[64 * 40];
  __shared__ __align__(16) unsigned short Hs[64 * 136];
  __shared__ __align__(16) unsigned short H2s[64 * 72];
  __shared__ float Ms[2][64][32];
  __shared__ float Red[2][64];
  __shared__ float u_s[64];
  const int tid = threadIdx.x, w = tid >> 6, l = tid & 63;
  const int lr = l & 15, lh = l >> 4;
  const int mt = w & 3, nh = w >> 2;
  const int r0 = blockIdx.x * 64;
  const short8* w1v = (const short8*)w1f;
  const short8* w2v = (const short8*)w2f;
  const short8* w3v = (const short8*)w3f;

  const int nsteps = phase ? 1 : 3;
  const int sroot = 3 + blockIdx.y;

  for (int step = 0; step < nsteps; step++) {
    int node, sl = 0, sr = 0, os = -1;
    bool haveCh;
    if (phase) {
      node = node_base + blockIdx.y; haveCh = true;
    } else {
      switch (step) {
        case 0: node = 2 * sroot + 1; haveCh = false; os = 0; break;
        case 1: node = 2 * sroot + 2; haveCh = false; os = 1; break;
        default: node = sroot; haveCh = true; sl = 0; sr = 1; os = -1; break;
      }
    }
    const int rbase = (node << LOGB) + r0;

    for (int f = tid; f < 64 * 32; f += 512) {
      int r = f >> 5, c = f & 31;
      Xs[r * 40 + c] = f2bf(x[(rbase + r) * 32 + c]);
    }
    if (tid < 64) u_s[tid] = u[rbase + tid];
    if (haveCh) {
      for (int f = tid; f < 64 * 64; f += 512) {
        int r = f >> 6, c = f & 63;
        float v;
        if (phase)
          v = (c < 32) ? msg_up[(((2 * node + 1) << LOGB) + r0 + r) * 32 + c]
                       : msg_up[(((2 * node + 2) << LOGB) + r0 + r) * 32 + (c - 32)];
        else
          v = (c < 32) ? Ms[sl][r][c] : Ms[sr][r][c - 32];
        Hs[r * 136 + 64 + c] = f2bf(tanh_fast(v));
      }
    }
    __syncthreads();

    f32x4 acc1[2];
#pragma unroll
    for (int t = 0; t < 2; t++) acc1[t] = (f32x4)(0.f);
    {
      short8 a = *(const short8*)&Xs[(mt * 16 + lr) * 40 + lh * 8];
#pragma unroll
      for (int t = 0; t < 2; t++)
        acc1[t] = __builtin_amdgcn_mfma_f32_16x16x32_bf16(a, w1v[(nh * 2 + t) * 64 + l], acc1[t], 0, 0, 0);
    }
    float v1[2][4];
    {
      float vsq[4] = {0.f, 0.f, 0.f, 0.f};
#pragma unroll
      for (int t = 0; t < 2; t++) {
        int n = (nh * 2 + t) * 16 + lr;
        float wu = w1raw[n * 33 + 32];
        float bb = b1[n];
#pragma unroll
        for (int r = 0; r < 4; r++) {
          float vv = acc1[t][r] + u_s[mt * 16 + lh * 4 + r] * wu + bb;
          v1[t][r] = vv;
          vsq[r] += vv * vv;
        }
      }
#pragma unroll
      for (int r = 0; r < 4; r++) {
        float s = vsq[r];
        s += __shfl_xor(s, 1, 64);
        s += __shfl_xor(s, 2, 64);
        s += __shfl_xor(s, 4, 64);
        s += __shfl_xor(s, 8, 64);
        if (lr == 0) Red[nh][mt * 16 + lh * 4 + r] = s;
      }
    }
    __syncthreads();
#pragma unroll
    for (int r = 0; r < 4; r++) {
      int row = mt * 16 + lh * 4 + r;
      float inv = 1.f / fmaxf(sqrtf(Red[0][row] + Red[1][row]), 1e-12f);
#pragma unroll
      for (int t = 0; t < 2; t++)
        Hs[row * 136 + (nh * 2 + t) * 16 + lr] = f2bf(tanh_fast(v1[t][r] * inv));
    }
    __syncthreads();

    f32x4 acc2[2];
#pragma unroll
    for (int t = 0; t < 2; t++) acc2[t] = (f32x4)(0.f);
    const int ksmax = haveCh ? 4 : 2;
#pragma unroll
    for (int ks = 0; ks < 4; ks++) {
      if (ks < ksmax) {
        short8 a = *(const short8*)&Hs[(mt * 16 + lr) * 136 + ks * 32 + lh * 8];
#pragma unroll
        for (int t = 0; t < 2; t++)
          acc2[t] = __builtin_amdgcn_mfma_f32_16x16x32_bf16(a, w2v[((nh * 2 + t) * 4 + ks) * 64 + l], acc2[t], 0, 0, 0);
      }
    }
#pragma unroll
    for (int t = 0; t < 2; t++) {
      int n = (nh * 2 + t) * 16 + lr;
      float bb = b2[n];
#pragma unroll
      for (int r = 0; r < 4; r++)
        H2s[(mt * 16 + lh * 4 + r) * 72 + n] = f2bf(tanh_fast(acc2[t][r] + bb));
    }
    __syncthreads();

    f32x4 acc3 = (f32x4)(0.f);
#pragma unroll
    for (int ks = 0; ks < 2; ks++) {
      short8 a = *(const short8*)&H2s[(mt * 16 + lr) * 72 + ks * 32 + lh * 8];
      acc3 = __builtin_amdgcn_mfma_f32_16x16x32_bf16(a, w3v[(nh * 2 + ks) * 64 + l], acc3, 0, 0, 0);
    }
    float v3[4];
    {
      float bb = b3[nh * 16 + lr];
#pragma unroll
      for (int r = 0; r < 4; r++) {
        v3[r] = acc3[r] + bb;
        float s = v3[r] * v3[r];
        s += __shfl_xor(s, 1, 64);
        s += __shfl_xor(s, 2, 64);
        s += __shfl_xor(s, 4, 64);
        s += __shfl_xor(s, 8, 64);
        if (lr == 0) Red[nh][mt * 16 + lh * 4 + r] = s;
      }
    }
    __syncthreads();
    {
      const int n = nh * 16 + lr;
#pragma unroll
      for (int r = 0; r < 4; r++) {
        int row = mt * 16 + lh * 4 + r;
        float inv = 1.f / fmaxf(sqrtf(Red[0][row] + Red[1][row]), 1e-12f);
        float mv = v3[r] * inv;
        msg_up[(rbase + row) * 32 + n] = mv;
        if (os >= 0) Ms[os][row][n] = mv;
      }
    }
    __syncthreads();
  }
}

// ---------------- mb chain: 512 threads, global-chained msg_in, 8-wave layer 3 ----------------
__global__ __launch_bounds__(512, 2) void k_mb_fused(
    const float* __restrict__ msg_up,
    const unsigned short* __restrict__ w1f, const unsigned short* __restrict__ w2f,
    const unsigned short* __restrict__ w3f,
    const float* __restrict__ b1, const float* __restrict__ b2, const float* __restrict__ b3,
    float* __restrict__ msg_in_out) {
  __shared__ __align__(16) unsigned short H1s[32 * 424];
  __shared__ __align__(16) unsigned short H2s[32 * 328];
  __shared__ __align__(16) unsigned char XR[32 * 72 * 2];
  unsigned short* Xs = (unsigned short*)XR;
  float* RedM = (float*)XR;
  const int tid = threadIdx.x;
  const int r0 = blockIdx.x * 32;
  const int w = tid >> 6, l = tid & 63;
  const int lr = l & 15, lh = l >> 4;
  const short8* w1v = (const short8*)w1f;
  const short8* w2v = (const short8*)w2f;
  const short8* w3v = (const short8*)w3f;

  for (int f = tid; f < 32 * 16; f += 512)
    H1s[(f >> 4) * 424 + 400 + (f & 15)] = 0;
  for (int f = tid; f < 32 * 16; f += 512)
    H2s[(f >> 4) * 328 + 304 + (f & 15)] = 0;

  for (int node = 0; node < 7; node++) {
    const int rbase = (node << LOGB) + r0;
    for (int f = tid; f < 32 * 64; f += 512) {
      int r = f >> 6, c = f & 63;
      float v;
      if (c < 32) v = msg_up[(rbase + r) * 32 + c];
      else v = (node > 0) ? msg_in_out[(rbase + r) * 32 + (c - 32)] : 0.f;
      Xs[r * 72 + c] = f2bf(tanh_fast(v));
    }
    __syncthreads();

    const int nb1 = (w == 0) ? 0 : (3 * w + 1);
    const int nc1 = (w == 0) ? 4 : 3;
    f32x4 acc1[4][2];
#pragma unroll
    for (int i = 0; i < 4; i++)
#pragma unroll
      for (int m = 0; m < 2; m++) acc1[i][m] = (f32x4)(0.f);
    __builtin_amdgcn_s_setprio(1);
#pragma unroll
    for (int ks = 0; ks < 2; ks++) {
      short8 bx[2];
#pragma unroll
      for (int m = 0; m < 2; m++)
        bx[m] = *(const short8*)&Xs[(m * 16 + lr) * 72 + ks * 32 + lh * 8];
      short8 aw[4];
#pragma unroll
      for (int nt = 0; nt < 4; nt++)
        if (nt < nc1) aw[nt] = w1v[((nb1 + nt) * 2 + ks) * 64 + l];
#pragma unroll
      for (int nt = 0; nt < 4; nt++)
        if (nt < nc1)
#pragma unroll
          for (int m = 0; m < 2; m++)
            acc1[nt][m] = __builtin_amdgcn_mfma_f32_16x16x32_bf16(aw[nt], bx[m], acc1[nt][m], 0, 0, 0);
    }
    __builtin_amdgcn_s_setprio(0);
#pragma unroll
    for (int nt = 0; nt < 4; nt++)
      if (nt < nc1) {
        int n0 = (nb1 + nt) * 16 + lh * 4;
        float4 bb = *(const float4*)&b1[n0];
#pragma unroll
        for (int m = 0; m < 2; m++) {
          float h0 = fmaxf(acc1[nt][m][0] + bb.x, 0.f);
          float h1 = fmaxf(acc1[nt][m][1] + bb.y, 0.f);
          float h2 = fmaxf(acc1[nt][m][2] + bb.z, 0.f);
          float h3 = fmaxf(acc1[nt][m][3] + bb.w, 0.f);
          *(uint2*)&H1s[(m * 16 + lr) * 424 + n0] = pack4bf(h0, h1, h2, h3);
        }
      }
    __syncthreads();

    const int nb2 = (w < 3) ? 3 * w : (9 + 2 * (w - 3));
    const int nc2 = (w < 3) ? 3 : 2;
    f32x4 acc2[3][2];
#pragma unroll
    for (int i = 0; i < 3; i++)
#pragma unroll
      for (int m = 0; m < 2; m++) acc2[i][m] = (f32x4)(0.f);
    __builtin_amdgcn_s_setprio(1);
#pragma unroll 2
    for (int ks = 0; ks < 13; ks++) {
      short8 bh[2];
#pragma unroll
      for (int m = 0; m < 2; m++)
        bh[m] = *(const short8*)&H1s[(m * 16 + lr) * 424 + ks * 32 + lh * 8];
      short8 aw[3];
#pragma unroll
      for (int nt = 0; nt < 3; nt++)
        if (nt < nc2) aw[nt] = w2v[((nb2 + nt) * 13 + ks) * 64 + l];
#pragma unroll
      for (int nt = 0; nt < 3; nt++)
        if (nt < nc2)
#pragma unroll
          for (int m = 0; m < 2; m++)
            acc2[nt][m] = __builtin_amdgcn_mfma_f32_16x16x32_bf16(aw[nt], bh[m], acc2[nt][m], 0, 0, 0);
    }
    __builtin_amdgcn_s_setprio(0);
#pragma unroll
    for (int nt = 0; nt < 3; nt++)
      if (nt < nc2) {
        int n0 = (nb2 + nt) * 16 + lh * 4;
        float b2v[4];
#pragma unroll
        for (int r = 0; r < 4; r++) {
          int n = n0 + r;
          b2v[r] = (n < 300) ? b2[n] : 0.f;
        }
#pragma unroll
        for (int m = 0; m < 2; m++) {
          float hv[4];
#pragma unroll
          for (int r = 0; r < 4; r++)
            hv[r] = (n0 + r < 300) ? fmaxf(acc2[nt][m][r] + b2v[r], 0.f) : 0.f;
          *(uint2*)&H2s[(m * 16 + lr) * 328 + n0] = pack4bf(hv[0], hv[1], hv[2], hv[3]);
        }
      }
    __syncthreads();

    float v3[4];
    {
      const int mL3 = w >> 2;
      const int nt3 = w & 3;
      f32x4 acc3 = (f32x4)(0.f);
      __builtin_amdgcn_s_setprio(1);
#pragma unroll 2
      for (int ks = 0; ks < 10; ks++) {
        short8 bh = *(const short8*)&H2s[(mL3 * 16 + lr) * 328 + ks * 32 + lh * 8];
        short8 aw = w3v[(nt3 * 10 + ks) * 64 + l];
        acc3 = __builtin_amdgcn_mfma_f32_16x16x32_bf16(aw, bh, acc3, 0, 0, 0);
      }
      __builtin_amdgcn_s_setprio(0);
      int n0 = nt3 * 16 + lh * 4;
      float4 bb = *(const float4*)&b3[n0];
      v3[0] = acc3[0] + bb.x;
      v3[1] = acc3[1] + bb.y;
      v3[2] = acc3[2] + bb.z;
      v3[3] = acc3[3] + bb.w;
      float ss = v3[0] * v3[0] + v3[1] * v3[1] + v3[2] * v3[2] + v3[3] * v3[3];
      ss += __shfl_xor(ss, 16, 64);
      ss += __shfl_xor(ss, 32, 64);
      if (l < 16) RedM[nt3 * 32 + mL3 * 16 + l] = ss;
    }
    __syncthreads();
    {
      const int mL3 = w >> 2;
      const int nt3 = w & 3;
      const int row = mL3 * 16 + lr;
      float ss = RedM[0 * 32 + row] + RedM[1 * 32 + row] + RedM[2 * 32 + row] + RedM[3 * 32 + row];
      float inv = 1.f / fmaxf(sqrtf(ss), 1e-12f);
      const int child = 2 * node + 1 + (nt3 >> 1);
      const int ccol0 = (nt3 & 1) * 16 + lh * 4;
      float4 o;
      o.x = v3[0] * inv; o.y = v3[1] * inv;
      o.z = v3[2] * inv; o.w = v3[3] * inv;
      *(float4*)&msg_in_out[((child << LOGB) + r0 + row) * 32 + ccol0] = o;
    }
    __syncthreads();
  }
}

// ---------------- Q nets: 512 threads, 64 rows/block, swapped MFMA ----------------
__global__ __launch_bounds__(512, 4) void k_q_mfma(
    const float* __restrict__ msg_up, const float* __restrict__ u,
    const float* __restrict__ msg_in,
    const unsigned short* __restrict__ w1fA, const unsigned short* __restrict__ w2fA,
    const float* __restrict__ wuA, const float* __restrict__ b1A,
    const float* __restrict__ b2A, const float* __restrict__ w3A, const float* __restrict__ b3A,
    const unsigned short* __restrict__ w1fB, const unsigned short* __restrict__ w2fB,
    const float* __restrict__ wuB, const float* __restrict__ b1B,
    const float* __restrict__ b2B, const float* __restrict__ w3B, const float* __restrict__ b3B,
    float* __restrict__ out) {
  __shared__ __align__(16) unsigned char sraw[64 * 72 * 2];
  __shared__ __align__(16) unsigned short H1s[64 * 424];
  __shared__ float u_s[64];
  unsigned short* Xs = (unsigned short*)sraw;
  float* Red = (float*)sraw;

  const int tid = threadIdx.x;
  const int net = blockIdx.y;
  const unsigned short* w1f = net ? w1fB : w1fA;
  const unsigned short* w2f = net ? w2fB : w2fA;
  const float* wua = net ? wuB : wuA;
  const float* b1 = net ? b1B : b1A;
  const float* b2 = net ? b2B : b2A;
  const float* w3 = net ? w3B : w3A;
  const float* b3 = net ? b3B : b3A;
  const int r0 = blockIdx.x * 64;
  const int node = r0 >> LOGB;
  const int has_parent = (node > 0);
  const short8* w1v = (const short8*)w1f;
  const short8* w2v = (const short8*)w2f;

  {
    const int r = tid >> 3, seg = tid & 7;
    float4 v0, v1;
    if (seg < 4) {
      const float4* p = (const float4*)&msg_up[(r0 + r) * 32 + seg * 8];
      v0 = p[0]; v1 = p[1];
    } else if (has_parent) {
      const float4* p = (const float4*)&msg_in[(r0 + r) * 32 + (seg - 4) * 8];
      v0 = p[0]; v1 = p[1];
    } else {
      v0 = make_float4(0.f, 0.f, 0.f, 0.f); v1 = v0;
    }
    unsigned short tmp[8] = {f2bf(v0.x), f2bf(v0.y), f2bf(v0.z), f2bf(v0.w),
                             f2bf(v1.x), f2bf(v1.y), f2bf(v1.z), f2bf(v1.w)};
    *(short8*)&Xs[r * 72 + seg * 8] = *(const short8*)tmp;
  }
  for (int f = tid; f < 64 * 16; f += 512)
    H1s[(f >> 4) * 424 + 400 + (f & 15)] = 0;
  if (tid < 64) u_s[tid] = u[r0 + tid];
  __syncthreads();

  const int w = tid >> 6, l = tid & 63;
  const int lr = l & 15, lh = l >> 4;

  const int nb1 = (w == 0) ? 0 : (3 * w + 1);
  const int nc1 = (w == 0) ? 4 : 3;
  f32x4 acc1[4][4];
#pragma unroll
  for (int i = 0; i < 4; i++)
#pragma unroll
    for (int m = 0; m < 4; m++) acc1[i][m] = (f32x4)(0.f);
  __builtin_amdgcn_s_setprio(1);
#pragma unroll
  for (int ks = 0; ks < 2; ks++) {
    short8 bx[4];
#pragma unroll
    for (int m = 0; m < 4; m++)
      bx[m] = *(const short8*)&Xs[(m * 16 + lr) * 72 + ks * 32 + lh * 8];
    short8 aw[4];
#pragma unroll
    for (int nt = 0; nt < 4; nt++)
      if (nt < nc1) aw[nt] = w1v[((nb1 + nt) * 2 + ks) * 64 + l];
#pragma unroll
    for (int nt = 0; nt < 4; nt++)
      if (nt < nc1)
#pragma unroll
        for (int m = 0; m < 4; m++)
          acc1[nt][m] = __builtin_amdgcn_mfma_f32_16x16x32_bf16(aw[nt], bx[m], acc1[nt][m], 0, 0, 0);
  }
  __builtin_amdgcn_s_setprio(0);
#pragma unroll
  for (int nt = 0; nt < 4; nt++)
    if (nt < nc1) {
      int n0 = (nb1 + nt) * 16 + lh * 4;
      float4 bb = *(const float4*)&b1[n0];
      float4 wu = *(const float4*)&wua[n0];
#pragma unroll
      for (int m = 0; m < 4; m++) {
        float uv = u_s[m * 16 + lr];
        float h0 = fmaxf(acc1[nt][m][0] + uv * wu.x + bb.x, 0.f);
        float h1 = fmaxf(acc1[nt][m][1] + uv * wu.y + bb.y, 0.f);
        float h2 = fmaxf(acc1[nt][m][2] + uv * wu.z + bb.z, 0.f);
        float h3 = fmaxf(acc1[nt][m][3] + uv * wu.w + bb.w, 0.f);
        *(uint2*)&H1s[(m * 16 + lr) * 424 + n0] = pack4bf(h0, h1, h2, h3);
      }
    }
  __syncthreads();

  const int nb2 = (w < 3) ? 3 * w : (9 + 2 * (w - 3));
  const int nc2 = (w < 3) ? 3 : 2;
  f32x4 acc2[3][4];
#pragma unroll
  for (int i = 0; i < 3; i++)
#pragma unroll
    for (int m = 0; m < 4; m++) acc2[i][m] = (f32x4)(0.f);
  __builtin_amdgcn_s_setprio(1);
#pragma unroll 2
  for (int ks = 0; ks < 13; ks++) {
    short8 bh[4];
#pragma unroll
    for (int m = 0; m < 4; m++)
      bh[m] = *(const short8*)&H1s[(m * 16 + lr) * 424 + ks * 32 + lh * 8];
    short8 aw[3];
#pragma unroll
    for (int nt = 0; nt < 3; nt++)
      if (nt < nc2) aw[nt] = w2v[((nb2 + nt) * 13 + ks) * 64 + l];
#pragma unroll
    for (int nt = 0; nt < 3; nt++)
      if (nt < nc2)
#pragma unroll
        for (int m = 0; m < 4; m++)
          acc2[nt][m] = __builtin_amdgcn_mfma_f32_16x16x32_bf16(aw[nt], bh[m], acc2[nt][m], 0, 0, 0);
  }
  __builtin_amdgcn_s_setprio(0);
  float part[4];
#pragma unroll
  for (int m = 0; m < 4; m++) part[m] = 0.f;
#pragma unroll
  for (int nt = 0; nt < 3; nt++)
    if (nt < nc2) {
      int n0 = (nb2 + nt) * 16 + lh * 4;
      float b2v[4], w3v4[4];
#pragma unroll
      for (int r = 0; r < 4; r++) {
        int n = n0 + r;
        b2v[r] = (n < 300) ? b2[n] : 0.f;
        w3v4[r] = (n < 300) ? w3[n] : 0.f;
      }
#pragma unroll
      for (int m = 0; m < 4; m++)
#pragma unroll
        for (int r = 0; r < 4; r++) {
          float h = fmaxf(acc2[nt][m][r] + b2v[r], 0.f);
          part[m] = fmaf(h, w3v4[r], part[m]);
        }
    }
#pragma unroll
  for (int m = 0; m < 4; m++) {
    float p = part[m];
    p += __shfl_xor(p, 16, 64);
    p += __shfl_xor(p, 32, 64);
    if (l < 16) Red[w * 64 + m * 16 + l] = p;
  }
  __syncthreads();
  if (tid < 64) {
    float q = b3[0];
#pragma unroll
    for (int i = 0; i < 8; i++) q += Red[i * 64 + tid];
    out[(r0 + tid) * 2 + net] = q;
  }
}

extern "C" void kernel_launch(void* const* d_in, const int* in_sizes, int n_in,
                              void* d_out, int out_size, void* d_ws, size_t ws_size,
                              hipStream_t stream) {
  const float* x    = (const float*)d_in[0];
  const float* u    = (const float*)d_in[1];
  const float* up1w = (const float*)d_in[2];  const float* up1b = (const float*)d_in[3];
  const float* up2w = (const float*)d_in[4];  const float* up2b = (const float*)d_in[5];
  const float* up3w = (const float*)d_in[6];  const float* up3b = (const float*)d_in[7];
  const float* q1w1 = (const float*)d_in[8];  const float* q1b1 = (const float*)d_in[9];
  const float* q1w2 = (const float*)d_in[10]; const float* q1b2 = (const float*)d_in[11];
  const float* q1w3 = (const float*)d_in[12]; const float* q1b3 = (const float*)d_in[13];
  const float* q2w1 = (const float*)d_in[14]; const float* q2b1 = (const float*)d_in[15];
  const float* q2w2 = (const float*)d_in[16]; const float* q2b2 = (const float*)d_in[17];
  const float* q2w3 = (const float*)d_in[18]; const float* q2b3 = (const float*)d_in[19];
  const float* mbw1 = (const float*)d_in[20]; const float* mbb1 = (const float*)d_in[21];
  const float* mbw2 = (const float*)d_in[22]; const float* mbb2 = (const float*)d_in[23];
  const float* mbw3 = (const float*)d_in[24]; const float* mbb3 = (const float*)d_in[25];
  float* out = (float*)d_out;
  float* ws  = (float*)d_ws;

  float* msg_up = ws;
  float* msg_in = msg_up + 15 * BN * 32;
  unsigned short* frag = (unsigned short*)(msg_in + 15 * BN * 32);
  unsigned short* q1w1f = frag;
  unsigned short* q1w2f = q1w1f + 25600;
  unsigned short* q2w1f = q1w2f + 126464;
  unsigned short* q2w2f = q2w1f + 25600;
  unsigned short* mbw1f = q2w2f + 126464;
  unsigned short* mbw2f = mbw1f + 25600;
  unsigned short* mbw3f = mbw2f + 126464;
  unsigned short* up1f  = mbw3f + 20480;
  unsigned short* up2f  = up1f + 2048;
  unsigned short* up3f  = up2f + 8192;
  float* wuQ1 = (float*)(up3f + 2048);
  float* wuQ2 = wuQ1 + 400;

  k_prep_pack<<<dim3((489760 + 255) / 256), dim3(256), 0, stream>>>(
      q1w1, q1w1f, q1w2, q1w2f, q2w1, q2w1f, q2w2, q2w2f,
      mbw1, mbw1f, mbw2, mbw2f, mbw3, mbw3f,
      up1w, up1f, up2w, up2f, up3w, up3f, wuQ1, wuQ2);

  k_up_mfma<<<dim3(BN / 64, 4), dim3(512), 0, stream>>>(
      x, u, up1f, up1w, up1b, up2f, up2b, up3f, up3b, msg_up, 0, 0);
  k_up_mfma<<<dim3(BN / 64, 2), dim3(512), 0, stream>>>(
      x, u, up1f, up1w, up1b, up2f, up2b, up3f, up3b, msg_up, 1, 1);
  k_up_mfma<<<dim3(BN / 64, 1), dim3(512), 0, stream>>>(
      x, u, up1f, up1w, up1b, up2f, up2b, up3f, up3b, msg_up, 1, 0);

  k_mb_fused<<<dim3(BN / 32), dim3(512), 0, stream>>>(
      msg_up, mbw1f, mbw2f, mbw3f, mbb1, mbb2, mbb3, msg_in);

  k_q_mfma<<<dim3(15 * (BN / 64), 2), dim3(512), 0, stream>>>(
      msg_up, u, msg_in,
      q1w1f, q1w2f, wuQ1, q1b1, q1b2, q1w3, q1b3,
      q2w1f, q2w2f, wuQ2, q2b1, q2b2, q2w3, q2b3,
      out);
}